// Round 1
// 235.739 us; speedup vs baseline: 1.0163x; 1.0163x over previous
//
#include <hip/hip_runtime.h>
#include <cstdint>
#include <cstddef>

#define HID 128
#define SEQL 28
#define INP 28
#define NL 10
#define NC 10
#define BATCH 4096
#define BB 16             // batch rows per block
#define STRD 136          // padded row stride in halfs (272 B, b128-aligned)
#define BUFH (16 * STRD)  // halfs per 16x128 activation buffer

typedef _Float16 half8 __attribute__((ext_vector_type(8)));
typedef _Float16 half4 __attribute__((ext_vector_type(4)));
typedef float    f32x4 __attribute__((ext_vector_type(4)));

// ---------------- ws layout (bytes) ----------------
// Wcat : [NL][HID][256] f16 : 655360 @ 0   row n: [Wih(128, l0 zero-padded) | Whh(128)]
// bias : [NL][HID] f32      : 5120   @ 655360   (b_ih + b_hh)
// seq  : [BATCH][SEQL][HID] f16 : 29360128 @ 660480 (group-boundary acts; reused h3 then h7)
#define WS_WCAT_OFF 0
#define WS_BIAS_OFF 655360
#define WS_SEQ_OFF  660480

__global__ void convert_weights(const float* __restrict__ Wih0,
                                const float* __restrict__ Wih,
                                const float* __restrict__ Whh,
                                const float* __restrict__ bih,
                                const float* __restrict__ bhh,
                                _Float16* __restrict__ Wcat,
                                float* __restrict__ bias) {
  int tg = blockIdx.x * blockDim.x + threadIdx.x;
  if (tg >= NL * HID * 16) return;
  int r = tg >> 4, seg = tg & 15;
  int l = r / HID, n = r % HID;
  int k0 = seg * 16;
  _Float16* dst = Wcat + (size_t)r * 256 + k0;
  if (l == 0) {
#pragma unroll
    for (int i = 0; i < 16; ++i) {
      int k = k0 + i;
      float v = 0.f;
      if (k < INP) v = Wih0[n * INP + k];
      else if (k >= HID) v = Whh[(size_t)n * HID + (k - HID)];
      dst[i] = (_Float16)v;
    }
  } else {
    const float* src = (k0 < HID)
        ? (Wih + ((size_t)(l - 1) * HID + n) * HID + k0)
        : (Whh + ((size_t)l * HID + n) * HID + (k0 - HID));
#pragma unroll
    for (int i = 0; i < 16; ++i) dst[i] = (_Float16)src[i];
  }
  if (seg == 0) bias[r] = bih[r] + bhh[r];
}

__device__ __forceinline__ float tanh_fast(float v) {
  float e = __expf(2.f * v);
  return 1.f - 2.f / (e + 1.f);
}

// 512 threads = 8 waves. Redesign vs round-3: pipeline depth 4 (3 groups of
// layers {0-3},{4-7},{8-9}); each cell (layer-slot s) is computed by a TEAM of
// 2 waves (wid = 2s + nhalf), each wave owning 64 n-columns. Weights for
// 64n x 256k live in 128 VGPRs/wave. Each A-frag ds_read_b128 now feeds 4
// MFMAs (was 1) -> per-cell LDS read traffic drops 64KB -> 16KB (the round-3
// bottleneck: all 8 waves re-read identical A-tiles).
// MFMA operands are SWAPPED (A=weights rows=n, B=activations cols=m): the C
// layout (col=lane&15 -> batch row m, row=quad*4+r -> n) makes each thread's
// 4 outputs n-consecutive at fixed m -> one aligned ds_write_b64 per subtile
// instead of 4 scattered ds_write_b16 (bank-conflict source).
// LDS slots (BUFH halfs): X(p)=slot p (p=0,1); O(s,p)=slot 2+2s+p, s=0..3.
// Tick tau, pt=tau&1: slot s computes t=tau-s; reads INb = s? O(s-1,1-pt) :
// X(pt), Hb = O(s,1-pt); writes O(s,pt). One barrier per tick.
// Group boundaries (layer 3->4, 7->8) go through the single global seq
// buffer: g1 reads h3[tau+1] while writing h7[tau-3] (always 4 apart, safe).
__global__ __launch_bounds__(512, 2) void rnn_fused(
    const float* __restrict__ x,
    const _Float16* __restrict__ Wcat,
    const float* __restrict__ bias,
    const float* __restrict__ fcW,
    const float* __restrict__ fcb,
    _Float16* __restrict__ seq,
    float* __restrict__ out) {
  __shared__ _Float16 lds[BUFH * 10] __attribute__((aligned(16)));

  const int tid    = threadIdx.x;
  const int lane15 = tid & 15;        // batch row m (MFMA D col)
  const int quad   = (tid >> 4) & 3;  // MFMA quad -> n offset quad*4+r
  const int wid    = tid >> 6;
  const int s      = wid >> 1;        // layer slot 0..3
  const int nhalf  = wid & 1;         // n-half 0/1
  const int n0     = nhalf * 64;
  const int b0     = blockIdx.x * BB;
  // g>=1 fill: 16 rows x 32 segs of 4 halfs (512 threads)
  const int frow1  = tid >> 5;
  const int fseg1  = tid & 31;
  // g0 fill: 16 rows x 8 segs of 4 floats (128 threads)
  const int frow0  = tid >> 3;
  const int fc0    = (tid & 7) * 4;

  const int rdoff = lane15 * STRD + quad * 8;       // B-frag (act) read base
  const int wroff = lane15 * STRD + n0 + quad * 4;  // D write base (+nn*16)

  half8 wf[4][8];     // weights [n-subtile][k-frag]: A-operand frags
  f32x4 bias4[4];     // bias[n0+nn*16+quad*4 .. +3]

  for (int g = 0; g < 3; ++g) {
    const int L = g * 4 + s;  // this wave's layer (>=NL -> idle slot)
    if (L < NL) {
      const _Float16* Wl = Wcat + (size_t)L * HID * 256;
#pragma unroll
      for (int nn = 0; nn < 4; ++nn) {
#pragma unroll
        for (int ks = 0; ks < 8; ++ks)
          wf[nn][ks] = *(const half8*)(Wl + (size_t)(n0 + nn * 16 + lane15) * 256 + ks * 32 + quad * 8);
        bias4[nn] = *(const f32x4*)(bias + L * HID + n0 + nn * 16 + quad * 4);
      }
    }
    __syncthreads();  // prev group's LDS reads complete before re-zeroing
    {
      uint4 z; z.x = z.y = z.z = z.w = 0u;
      for (int i = tid; i < (BUFH * 8) / 8; i += 512)
        ((uint4*)(lds + 2 * BUFH))[i] = z;
    }

    float pfx[4];  // g0 prefetch (f32 x)
    uint2 pfu;     // g1/g2 prefetch (f16 seq)

    auto load_next = [&](int t) {
      if (g == 0) {
        if (tid < 128) {
          const float* xb = x + ((size_t)(b0 + frow0) * SEQL + t) * INP;
#pragma unroll
          for (int i = 0; i < 4; ++i) pfx[i] = (fc0 + i < INP) ? xb[fc0 + i] : 0.f;
        }
      } else {
        pfu = *(const uint2*)(seq + ((size_t)(b0 + frow1) * SEQL + t) * HID + fseg1 * 4);
      }
    };
    auto store_X = [&](int slot) {
      if (g == 0) {
        if (tid < 128) {
          _Float16 h4[4];
#pragma unroll
          for (int i = 0; i < 4; ++i) h4[i] = (_Float16)pfx[i];
          *(uint2*)(lds + slot * BUFH + frow0 * STRD + fc0) = *(const uint2*)h4;
        }
      } else {
        *(uint2*)(lds + slot * BUFH + frow1 * STRD + fseg1 * 4) = pfu;
      }
    };

    // prefill X[0] with t=0 input (visible after tick-0 barrier)
    load_next(0);
    store_X(0);

    auto tick = [&](int tau, int pt) {
      __syncthreads();
      const bool hn = (tau + 1) < SEQL;
      if (hn) load_next(tau + 1);  // global load issued early, consumed at end
      const int t = tau - s;
      if (L < NL && (unsigned)t < SEQL) {
        const _Float16* INb = (s == 0) ? lds + pt * BUFH
                                       : lds + (2 + 2 * (s - 1) + (1 - pt)) * BUFH;
        const _Float16* Hb  = lds + (2 + 2 * s + (1 - pt)) * BUFH;
        _Float16*       Ob  = lds + (2 + 2 * s + pt) * BUFH;

        f32x4 acc[4];
#pragma unroll
        for (int nn = 0; nn < 4; ++nn) acc[nn] = bias4[nn];

        if (g == 0 && s == 0) {
          // layer 0: x-input is only 32 k-wide (28 + pad); X pad beyond 32 is stale
          half8 a = *(const half8*)(INb + rdoff);
#pragma unroll
          for (int nn = 0; nn < 4; ++nn)
            acc[nn] = __builtin_amdgcn_mfma_f32_16x16x32_f16(wf[nn][0], a, acc[nn], 0, 0, 0);
        } else {
#pragma unroll
          for (int ks = 0; ks < 4; ++ks) {
            half8 a = *(const half8*)(INb + rdoff + ks * 32);
#pragma unroll
            for (int nn = 0; nn < 4; ++nn)
              acc[nn] = __builtin_amdgcn_mfma_f32_16x16x32_f16(wf[nn][ks], a, acc[nn], 0, 0, 0);
          }
        }
#pragma unroll
        for (int ks = 0; ks < 4; ++ks) {
          half8 a = *(const half8*)(Hb + rdoff + ks * 32);
#pragma unroll
          for (int nn = 0; nn < 4; ++nn)
            acc[nn] = __builtin_amdgcn_mfma_f32_16x16x32_f16(wf[nn][4 + ks], a, acc[nn], 0, 0, 0);
        }

        const bool wseq = (g < 2) && (s == 3);  // layers 3 and 7 -> global handoff
#pragma unroll
        for (int nn = 0; nn < 4; ++nn) {
          half4 o;
#pragma unroll
          for (int r = 0; r < 4; ++r) o[r] = (_Float16)tanh_fast(acc[nn][r]);
          *(half4*)(Ob + wroff + nn * 16) = o;
          if (wseq)
            *(half4*)(seq + ((size_t)(b0 + lane15) * SEQL + t) * HID + n0 + nn * 16 + quad * 4) = o;
        }
      }
      if (hn) store_X(1 - pt);  // X[(tau+1)&1]: nobody reads it this tick
    };

    const int Tend = (g == 2) ? 28 : 30;  // even; ticks 0..Tend
    for (int tau = 0; tau < Tend; tau += 2) {
      tick(tau, 0);
      tick(tau + 1, 1);
    }
    tick(Tend, 0);
  }
  __syncthreads();

  // --- FC on layer-9 h at t=27: slot s=1, written at g2 tick 28 (pt=0) -> slot 4 ---
  if (tid < BB * NC) {
    int c = tid >> 4;
    int b = tid & 15;
    float acc = fcb[c];
    const float* wr = fcW + c * HID;
    const _Float16* hr = lds + BUFH * 4 + b * STRD;
#pragma unroll
    for (int k0 = 0; k0 < HID; k0 += 8) {
      half8 h = *(const half8*)(hr + k0);
      f32x4 w0 = *(const f32x4*)(wr + k0);
      f32x4 w1 = *(const f32x4*)(wr + k0 + 4);
#pragma unroll
      for (int j = 0; j < 4; ++j)
        acc += (float)h[j] * w0[j] + (float)h[j + 4] * w1[j];
    }
    out[(size_t)(b0 + b) * NC + c] = acc;
  }
}

extern "C" void kernel_launch(void* const* d_in, const int* in_sizes, int n_in,
                              void* d_out, int out_size, void* d_ws, size_t ws_size,
                              hipStream_t stream) {
  const float* x    = (const float*)d_in[0];
  const float* Wih0 = (const float*)d_in[1];
  const float* Wih  = (const float*)d_in[2];
  const float* Whh  = (const float*)d_in[3];
  const float* bih  = (const float*)d_in[4];
  const float* bhh  = (const float*)d_in[5];
  const float* fcW  = (const float*)d_in[6];
  const float* fcb  = (const float*)d_in[7];
  float* out = (float*)d_out;

  _Float16* Wcat = (_Float16*)((char*)d_ws + WS_WCAT_OFF);
  float*    bs   = (float*)((char*)d_ws + WS_BIAS_OFF);
  _Float16* seq  = (_Float16*)((char*)d_ws + WS_SEQ_OFF);

  convert_weights<<<dim3(80), dim3(256), 0, stream>>>(Wih0, Wih, Whh, bih, bhh, Wcat, bs);
  rnn_fused<<<dim3(BATCH / BB), dim3(512), 0, stream>>>(x, Wcat, bs, fcW, fcb, seq, out);
}